// Round 1
// baseline (9.649 us; speedup 1.0000x reference)
//
#include <hip/hip_runtime.h>

// Householder reflection per batch row:
//   s_new[b] = s[b] - 2 * (v[b]·s[b]) / (v[b]·v[b]) * v[b]
// B = 512 rows, K = 512 cols, fp32.
// One 256-thread block per row; float2 per thread (512 floats/row).

#define K_DIM 512
#define THREADS 256

__global__ __launch_bounds__(THREADS) void householder_kernel(
    const float* __restrict__ v,
    const float* __restrict__ s,
    float* __restrict__ out) {
    const int b = blockIdx.x;
    const int tid = threadIdx.x;            // 0..255
    const size_t row = (size_t)b * K_DIM;

    const float2 vv2 = reinterpret_cast<const float2*>(v + row)[tid];
    const float2 ss2 = reinterpret_cast<const float2*>(s + row)[tid];

    float dvv = vv2.x * vv2.x + vv2.y * vv2.y;
    float dvs = vv2.x * ss2.x + vv2.y * ss2.y;

    // 64-lane wave reduction
    #pragma unroll
    for (int off = 32; off > 0; off >>= 1) {
        dvv += __shfl_down(dvv, off, 64);
        dvs += __shfl_down(dvs, off, 64);
    }

    __shared__ float svv[THREADS / 64];
    __shared__ float svs[THREADS / 64];
    const int wave = tid >> 6;
    const int lane = tid & 63;
    if (lane == 0) { svv[wave] = dvv; svs[wave] = dvs; }
    __syncthreads();

    const float tvv = svv[0] + svv[1] + svv[2] + svv[3];
    const float tvs = svs[0] + svs[1] + svs[2] + svs[3];
    const float scale = 2.0f * tvs / tvv;

    float2 o;
    o.x = ss2.x - scale * vv2.x;
    o.y = ss2.y - scale * vv2.y;
    reinterpret_cast<float2*>(out + row)[tid] = o;
}

extern "C" void kernel_launch(void* const* d_in, const int* in_sizes, int n_in,
                              void* d_out, int out_size, void* d_ws, size_t ws_size,
                              hipStream_t stream) {
    // Inputs (setup_inputs order): i (int scalar, unused), v [B,K] f32, s [B,K] f32
    const float* v = (const float*)d_in[1];
    const float* s = (const float*)d_in[2];
    float* out = (float*)d_out;
    const int B = in_sizes[1] / K_DIM;      // 512
    householder_kernel<<<B, THREADS, 0, stream>>>(v, s, out);
}

// Round 2
// 9.432 us; speedup vs baseline: 1.0229x; 1.0229x over previous
//
#include <hip/hip_runtime.h>

// Householder reflection per batch row:
//   s_new[b] = s[b] - 2 * (v[b]·s[b]) / (v[b]·v[b]) * v[b]
// B = 512 rows, K = 512 cols, fp32.
// One 64-lane wave per row; float4 x2 per lane (512 floats/row).
// Pure shfl_xor butterfly reduction: no LDS, no __syncthreads.

#define K_DIM 512
#define THREADS 64

__global__ __launch_bounds__(THREADS) void householder_kernel(
    const float* __restrict__ v,
    const float* __restrict__ s,
    float* __restrict__ out) {
    const int b = blockIdx.x;
    const int lane = threadIdx.x;           // 0..63
    const size_t row = (size_t)b * K_DIM;

    const float4* v4 = reinterpret_cast<const float4*>(v + row);
    const float4* s4 = reinterpret_cast<const float4*>(s + row);

    // Two float4 per lane: elements [lane*4 .. lane*4+3] and [+256 ..]
    const float4 va = v4[lane];
    const float4 vb = v4[lane + 64];
    const float4 sa = s4[lane];
    const float4 sb = s4[lane + 64];

    float dvv = va.x * va.x + va.y * va.y + va.z * va.z + va.w * va.w
              + vb.x * vb.x + vb.y * vb.y + vb.z * vb.z + vb.w * vb.w;
    float dvs = va.x * sa.x + va.y * sa.y + va.z * sa.z + va.w * sa.w
              + vb.x * sb.x + vb.y * sb.y + vb.z * sb.z + vb.w * sb.w;

    // 64-lane butterfly: every lane ends with the full sums.
    #pragma unroll
    for (int off = 32; off > 0; off >>= 1) {
        dvv += __shfl_xor(dvv, off, 64);
        dvs += __shfl_xor(dvs, off, 64);
    }

    const float scale = 2.0f * dvs / dvv;

    float4 oa, ob;
    oa.x = sa.x - scale * va.x;  oa.y = sa.y - scale * va.y;
    oa.z = sa.z - scale * va.z;  oa.w = sa.w - scale * va.w;
    ob.x = sb.x - scale * vb.x;  ob.y = sb.y - scale * vb.y;
    ob.z = sb.z - scale * vb.z;  ob.w = sb.w - scale * vb.w;

    float4* o4 = reinterpret_cast<float4*>(out + row);
    o4[lane] = oa;
    o4[lane + 64] = ob;
}

extern "C" void kernel_launch(void* const* d_in, const int* in_sizes, int n_in,
                              void* d_out, int out_size, void* d_ws, size_t ws_size,
                              hipStream_t stream) {
    // Inputs (setup_inputs order): i (int scalar, unused), v [B,K] f32, s [B,K] f32
    const float* v = (const float*)d_in[1];
    const float* s = (const float*)d_in[2];
    float* out = (float*)d_out;
    const int B = in_sizes[1] / K_DIM;      // 512
    householder_kernel<<<B, THREADS, 0, stream>>>(v, s, out);
}